// Round 7
// baseline (502.272 us; speedup 1.0000x reference)
//
#include <hip/hip_runtime.h>
#include <math.h>

#define NL 12

typedef short v8s __attribute__((ext_vector_type(8)));
typedef float v4f __attribute__((ext_vector_type(4)));

struct PrepArgs {
  const float* in[40];
  void* out[40];
  int n[40];      // input element count
  int mode[40];   // 0 plain f32, 1 transposed f32, 2 conv int-bf16, 3 conv1 CI3->4 pad
  int tc[40];     // mode1: minor dim
  int ci[40], kk[40], kp[40], co[40];   // mode2/3 geometry
};

// power-of-two scale: 2^ceil(log2(max(maxv,1e-8)/levels)).
// Bit-exact: for positive normal r, ceil(log2(r)) = (e-127) + (mantissa!=0).
__device__ inline float p2_scale_f(float maxv, float levels) {
  float r = __fdiv_rn(fmaxf(maxv, 1e-8f), levels);
  unsigned b = __float_as_uint(r);
  unsigned e = (b >> 23) & 0xffu;
  e += (b & 0x7fffffu) ? 1u : 0u;
  return __uint_as_float(e << 23);
}

// exact reciprocal of a power-of-two scale: 2^-k from 2^k by exponent flip
__device__ inline float p2_inv(float s) {
  return __uint_as_float((254u << 23) - __float_as_uint(s));
}

// blockDim must be 256. Result valid on thread 0. All threads must reach.
__device__ inline float block_reduce_max256(float v) {
  __shared__ float sm[4];
  #pragma unroll
  for (int off = 32; off; off >>= 1) v = fmaxf(v, __shfl_down(v, off));
  if ((threadIdx.x & 63) == 0) sm[threadIdx.x >> 6] = v;
  __syncthreads();
  if (threadIdx.x == 0) v = fmaxf(fmaxf(sm[0], sm[1]), fmaxf(sm[2], sm[3]));
  return v;
}

// v >= 0; non-negative float bits compare like unsigned. Read-skip cuts atomics.
__device__ inline void slot_max_update(float* slot, float v) {
  volatile unsigned int* su = (volatile unsigned int*)slot;
  unsigned int bits = __float_as_uint(v);
  if (bits > *su) atomicMax((unsigned int*)slot, bits);
}

// per-wave max + one guarded atomic; no barriers (max is order-invariant).
__device__ inline void wave_max_update(float v, float* slot) {
  #pragma unroll
  for (int off = 32; off; off >>= 1) v = fmaxf(v, __shfl_down(v, off));
  if ((threadIdx.x & 63) == 0) slot_max_update(slot, v);
}

// integer-valued float -> bf16 bits by truncation (exact for |v| <= 256)
__device__ inline short ibf16(float v) {
  return (short)(__float_as_uint(v) >> 16);
}

// blocks [0,40): per-tensor weight prep. blocks >=40: grid-stride max of x.
__global__ void prep_kernel(PrepArgs a, float* wslot,
                            const float* __restrict__ x, int nx, float* slot0) {
  if (blockIdx.x >= 40) {
    const float4* xv = (const float4*)x;
    const int nv = nx >> 2;
    float m0 = 0.f, m1 = 0.f, m2 = 0.f, m3 = 0.f;
    for (int i = (blockIdx.x - 40) * 256 + threadIdx.x; i < nv;
         i += (gridDim.x - 40) * 256) {
      float4 v = xv[i];
      m0 = fmaxf(m0, v.x); m1 = fmaxf(m1, v.y);
      m2 = fmaxf(m2, v.z); m3 = fmaxf(m3, v.w);
    }
    float m = fmaxf(fmaxf(m0, m1), fmaxf(m2, m3));
    wave_max_update(m, slot0);
    return;
  }
  __shared__ float ssc;
  const int t = blockIdx.x;
  const float* in = a.in[t];
  const int n = a.n[t], mode = a.mode[t];
  float m = 0.f;
  if (mode >= 2) {
    const float4* in4 = (const float4*)in;
    const int n4 = n >> 2;
    for (int i = threadIdx.x; i < n4; i += 256) {
      float4 v = in4[i];
      m = fmaxf(m, fmaxf(fmaxf(fabsf(v.x), fabsf(v.y)),
                         fmaxf(fabsf(v.z), fabsf(v.w))));
    }
  } else {
    for (int i = threadIdx.x; i < n; i += 256) m = fmaxf(m, fabsf(in[i]));
  }
  float bm = block_reduce_max256(m);
  if (threadIdx.x == 0) {
    ssc = p2_scale_f(bm, 127.0f);
    if (mode >= 2) wslot[t] = ssc;
  }
  __syncthreads();
  const float s = ssc;
  if (mode == 3) {
    // conv1 weight: layout [32][64], k = khkw*4 + ci (CI padded 3->4);
    // zero for ci==3, khkw>=9 -> kernel needs no k-mask.
    ushort* o = (ushort*)a.out[t];
    for (int i = threadIdx.x; i < 32 * 64; i += 256) {
      int co = i >> 6, k = i & 63;
      int khkw = k >> 2, ci = k & 3;
      ushort v = 0;
      if (khkw < 9 && ci < 3) {
        float q = rintf(__fdiv_rn(in[(co * 3 + ci) * 9 + khkw], s));
        q = fminf(fmaxf(q, -128.f), 127.f);
        v = (ushort)(__float_as_uint(q) >> 16);
      }
      o[i] = v;
    }
  } else if (mode == 2) {
    // conv weight: int codes as bf16, layout [Co][KP], k = khkw*Ci + ci, zero pad
    ushort* o = (ushort*)a.out[t];
    const int CI = a.ci[t], KK = a.kk[t], KP = a.kp[t], CO = a.co[t];
    const int KT = CI * KK;
    for (int i = threadIdx.x; i < CO * KP; i += 256) {
      int co = i / KP, k = i % KP;
      ushort v = 0;
      if (k < KT) {
        int khkw = k / CI, ci = k % CI;
        float q = rintf(__fdiv_rn(in[(co * CI + ci) * KK + khkw], s));
        q = fminf(fmaxf(q, -128.f), 127.f);
        v = (ushort)(__float_as_uint(q) >> 16);   // exact: |q| <= 128
      }
      o[i] = v;
    }
  } else {
    float* o = (float*)a.out[t];
    const int tc = a.tc[t];
    const int nw = (mode == 1) ? n / tc : 1;
    for (int i = threadIdx.x; i < n; i += 256) {
      float q = rintf(__fdiv_rn(in[i], s));
      q = fminf(fmaxf(q, -128.f), 127.f);
      float v = __fmul_rn(q, s);
      if (mode == 1) o[(i % nw) * tc + i / nw] = v;
      else o[i] = v;
    }
  }
}

// ---------- LDS-staged MFMA conv for K3 layers ----------
// Each block stages a contiguous TINxTIN NHWC tile with coalesced float4
// loads (quantizing ONCE per pixel) into LDS, then MFMA A-fragments come from
// ds_read_b128. Halo / out-of-image pixels are code 0 (= conv zero padding).
// Ragged edge tiles: stores and zmax are validity-guarded.
// CI=32 LDS layout: 8-short channel blocks XOR-rotated by ((p&3)<<3).

template <int CI, int H, int CO, bool POOL, int TOUT>
__global__ __launch_bounds__(256)
void conv_lds(const float* __restrict__ in, const short* __restrict__ wt,
              const float* __restrict__ sg, const float* __restrict__ sb,
              float* __restrict__ out, const float* __restrict__ slot_in,
              const float* __restrict__ wslotp, float* slot_out) {
  constexpr int W = H;
  constexpr int KT = 9 * CI;
  constexpr int SLABS = (KT + 31) / 32;
  constexpr int KP = SLABS * 32;
  constexpr int COT = CO / 16;
  constexpr int TIN = TOUT + 2;
  constexpr int NTL = (H + TOUT - 1) / TOUT;
  constexpr int PT = TOUT / 4;
  constexpr int NP = (PT * PT) / 4;     // patches per wave
  constexpr int HO = POOL ? H / 2 : H;
  constexpr int WO = POOL ? W / 2 : W;
  constexpr int LG = (CI == 16) ? 2 : 3;   // log2(CI/4)
  constexpr int CH = CI / 4;

  __shared__ ushort lds[TIN * TIN * CI];

  auto lidx = [](int pix, int cs) -> int {   // cs: short offset, multiple of 4
    if constexpr (CI == 32) return pix * CI + (cs ^ ((pix & 3) << 3));
    else return pix * CI + cs;
  };

  const int lane = threadIdx.x & 63, widx = threadIdx.x >> 6;
  const int quad = lane >> 4, col = lane & 15;
  const float s_in = p2_scale_f(slot_in[0], 255.0f);
  const float inv = p2_inv(s_in);
  const float S = __fmul_rn(s_in, wslotp[0]);

  const int bt = blockIdx.x;
  const int n = bt / (NTL * NTL);
  const int rr = bt % (NTL * NTL);
  const int ty = rr / NTL, tx = rr % NTL;
  const int gh0 = ty * TOUT - 1, gw0 = tx * TOUT - 1;
  const float* ib = in + (size_t)n * H * W * CI;

  for (int i = threadIdx.x; i < TIN * TIN * CH; i += 256) {
    const int pix = i >> LG, cg = i & (CH - 1);
    const int hi = pix / TIN, wi = pix - hi * TIN;
    const int gh = gh0 + hi, gw = gw0 + wi;
    float4 f = {0.f, 0.f, 0.f, 0.f};
    if ((unsigned)gh < (unsigned)H && (unsigned)gw < (unsigned)W)
      f = *(const float4*)(ib + ((size_t)(gh * W + gw)) * CI + cg * 4);
    ushort4 c;
    c.x = (ushort)ibf16(rintf(__fmul_rn(f.x, inv)));
    c.y = (ushort)ibf16(rintf(__fmul_rn(f.y, inv)));
    c.z = (ushort)ibf16(rintf(__fmul_rn(f.z, inv)));
    c.w = (ushort)ibf16(rintf(__fmul_rn(f.w, inv)));
    *(ushort4*)(lds + lidx(pix, cg * 4)) = c;
  }
  __syncthreads();

  v4f acc[NP][COT];
  #pragma unroll
  for (int p = 0; p < NP; p++)
    #pragma unroll
    for (int c = 0; c < COT; c++) acc[p][c] = (v4f){0.f, 0.f, 0.f, 0.f};

  #pragma unroll
  for (int slab = 0; slab < SLABS; slab++) {
    const int kbase = slab * 32 + quad * 8;
    int tap = kbase / CI; tap = min(tap, 8);
    const int cib = kbase % CI;
    const int kh = tap / 3, kw = tap - kh * 3;
    v8s b[COT];
    #pragma unroll
    for (int c = 0; c < COT; c++)
      b[c] = *(const v8s*)(wt + (size_t)(c * 16 + col) * KP + kbase);
    #pragma unroll
    for (int p = 0; p < NP; p++) {
      const int q = widx * NP + p;
      const int plh = (q / PT) * 4, plw = (q % PT) * 4;
      const int hin = plh + (col >> 2) + kh, win = plw + (col & 3) + kw;
      v8s a = *(const v8s*)(lds + lidx(hin * TIN + win, cib));
      #pragma unroll
      for (int c = 0; c < COT; c++)
        acc[p][c] = __builtin_amdgcn_mfma_f32_16x16x32_bf16(a, b[c], acc[p][c], 0, 0, 0);
    }
  }

  float zmax = 0.f;
  #pragma unroll
  for (int p = 0; p < NP; p++) {
    const int q = widx * NP + p;
    const int plh = (q / PT) * 4, plw = (q % PT) * 4;
    const int gho = ty * TOUT + plh, gwo = tx * TOUT + plw;
    #pragma unroll
    for (int c = 0; c < COT; c++) {
      const int cog = c * 16 + col;
      const float g = sg[cog], bb = sb[cog];
      float z[4];
      #pragma unroll
      for (int r2 = 0; r2 < 4; r2++) {
        float t = __fmul_rn(acc[p][c][r2], S);                  // exact
        z[r2] = fmaxf(__fadd_rn(__fmul_rn(t, g), bb), 0.f);     // matches XLA
      }
      if constexpr (POOL) {
        float h0 = fmaxf(z[0], z[1]), h1 = fmaxf(z[2], z[3]);
        float o0 = fmaxf(h0, __shfl_xor(h0, 16));
        float o1 = fmaxf(h1, __shfl_xor(h1, 16));
        const int oh = (gho >> 1) + (quad >> 1), ow = gwo >> 1;
        const bool v0 = (oh < HO) && (ow < WO), v1 = (oh < HO) && (ow + 1 < WO);
        zmax = fmaxf(zmax, fmaxf(v0 ? o0 : 0.f, v1 ? o1 : 0.f));
        if (!(quad & 1)) {
          float* op = out + ((size_t)((n * HO + oh) * WO + ow)) * CO + cog;
          if (v0) op[0] = o0;
          if (v1) op[CO] = o1;
        }
      } else {
        const int hh = gho + quad;
        #pragma unroll
        for (int r2 = 0; r2 < 4; r2++) {
          const int wwo = gwo + r2;
          if (hh < H && wwo < W) {
            out[(size_t)((n * H + hh) * W + wwo) * CO + cog] = z[r2];
            zmax = fmaxf(zmax, z[r2]);
          }
        }
      }
    }
  }
  wave_max_update(zmax, slot_out);
}

// conv1, LDS-staged, TOUT=32 (224/32=7 exact, zero ragged): stages+quantizes
// directly from NCHW f32 x into a 34x34x4 code tile (9.2KB LDS). K-layout
// k = khkw*4+ci (KP=64, 2 slabs), weights zero for ci==3 / khkw>=9 so no
// k-mask. Per wave: 16 patches processed serially with acc[2] reused
// (low VGPR); weights hoisted once. CO=32, pool 224->112, NHWC f32 out.
__global__ __launch_bounds__(256)
void conv1_lds(const float* __restrict__ x, const short* __restrict__ wt,
               const float* __restrict__ sg, const float* __restrict__ sb,
               float* __restrict__ out, const float* __restrict__ slot_in,
               const float* __restrict__ wslotp, float* slot_out) {
  constexpr int H = 224, W = 224, CO = 32, TOUT = 32, TIN = 34, NTL = 7;
  constexpr int HO = 112, WO = 112;
  __shared__ ushort lds[TIN * TIN * 4];

  const int lane = threadIdx.x & 63, widx = threadIdx.x >> 6;
  const int quad = lane >> 4, col = lane & 15;
  const float s_in = p2_scale_f(slot_in[0], 255.0f);
  const float inv = p2_inv(s_in);
  const float S = __fmul_rn(s_in, wslotp[0]);

  const int bt = blockIdx.x;
  const int n = bt / (NTL * NTL);
  const int rr = bt % (NTL * NTL);
  const int ty = rr / NTL, tx = rr % NTL;
  const int gh0 = ty * TOUT - 1, gw0 = tx * TOUT - 1;
  const float* xb = x + (size_t)n * 3 * H * W;

  for (int i = threadIdx.x; i < 3 * TIN * TIN; i += 256) {
    const int c = i / (TIN * TIN), pix = i - c * (TIN * TIN);
    const int hi = pix / TIN, wi = pix - hi * TIN;
    const int gh = gh0 + hi, gw = gw0 + wi;
    ushort code = 0;
    if ((unsigned)gh < (unsigned)H && (unsigned)gw < (unsigned)W)
      code = (ushort)ibf16(rintf(__fmul_rn(xb[(size_t)c * H * W + gh * W + gw], inv)));
    lds[pix * 4 + c] = code;
  }
  for (int i = threadIdx.x; i < TIN * TIN; i += 256) lds[i * 4 + 3] = 0;
  __syncthreads();

  // hoisted weight fragments: bfr[slab][c], kbase = slab*32 + quad*8
  v8s bfr[2][2];
  #pragma unroll
  for (int slab = 0; slab < 2; slab++) {
    bfr[slab][0] = *(const v8s*)(wt + (size_t)(col) * 64 + slab * 32 + quad * 8);
    bfr[slab][1] = *(const v8s*)(wt + (size_t)(16 + col) * 64 + slab * 32 + quad * 8);
  }
  // taps per (slab, quad): {slab*8+quad*2, +1}, clamped to 8 (zero weights pair)
  const int t0A = min(quad * 2, 8),     t0B = min(quad * 2 + 1, 8);
  const int t1A = min(8 + quad * 2, 8), t1B = min(8 + quad * 2 + 1, 8);

  auto read4 = [&](int ph, int pw, int tap) -> ushort4 {
    const int hin = ph + (col >> 2) + tap / 3, win = pw + (col & 3) + tap % 3;
    return ((const ushort4*)lds)[hin * TIN + win];
  };
  auto mka = [](ushort4 lo, ushort4 hi) -> v8s {
    v8s a;
    a[0] = (short)lo.x; a[1] = (short)lo.y; a[2] = (short)lo.z; a[3] = (short)lo.w;
    a[4] = (short)hi.x; a[5] = (short)hi.y; a[6] = (short)hi.z; a[7] = (short)hi.w;
    return a;
  };

  float zmax = 0.f;
  for (int p = widx; p < 64; p += 4) {       // 8x8 grid of 4x4 patches
    const int plh = (p >> 3) * 4, plw = (p & 7) * 4;
    v4f acc[2];
    acc[0] = (v4f){0.f, 0.f, 0.f, 0.f}; acc[1] = acc[0];
    {
      v8s a = mka(read4(plh, plw, t0A), read4(plh, plw, t0B));
      acc[0] = __builtin_amdgcn_mfma_f32_16x16x32_bf16(a, bfr[0][0], acc[0], 0, 0, 0);
      acc[1] = __builtin_amdgcn_mfma_f32_16x16x32_bf16(a, bfr[0][1], acc[1], 0, 0, 0);
    }
    {
      v8s a = mka(read4(plh, plw, t1A), read4(plh, plw, t1B));
      acc[0] = __builtin_amdgcn_mfma_f32_16x16x32_bf16(a, bfr[1][0], acc[0], 0, 0, 0);
      acc[1] = __builtin_amdgcn_mfma_f32_16x16x32_bf16(a, bfr[1][1], acc[1], 0, 0, 0);
    }
    const int gho = ty * TOUT + plh, gwo = tx * TOUT + plw;
    #pragma unroll
    for (int c = 0; c < 2; c++) {
      const int cog = c * 16 + col;
      const float g = sg[cog], bb = sb[cog];
      float z[4];
      #pragma unroll
      for (int r2 = 0; r2 < 4; r2++) {
        float t = __fmul_rn(acc[c][r2], S);
        z[r2] = fmaxf(__fadd_rn(__fmul_rn(t, g), bb), 0.f);
      }
      float h0 = fmaxf(z[0], z[1]), h1 = fmaxf(z[2], z[3]);
      float o0 = fmaxf(h0, __shfl_xor(h0, 16));
      float o1 = fmaxf(h1, __shfl_xor(h1, 16));
      zmax = fmaxf(zmax, fmaxf(o0, o1));   // 224%32==0: always valid
      if (!(quad & 1)) {
        const int oh = (gho >> 1) + (quad >> 1), ow = gwo >> 1;
        float* op = out + ((size_t)((n * HO + oh) * WO + ow)) * CO + cog;
        op[0] = o0; op[CO] = o1;
      }
    }
  }
  wave_max_update(zmax, slot_out);
}

// ---------- old implicit-GEMM conv, kept for K1 layers (dense gathers) ----------
template <int CI, int H, int CO, bool K3, bool POOL, int CSPLIT>
__global__ __launch_bounds__(256)
void conv_mfma(const float* __restrict__ in, const short* __restrict__ wt,
               const float* __restrict__ sg, const float* __restrict__ sb,
               float* __restrict__ out, const float* __restrict__ slot_in,
               const float* __restrict__ wslotp, float* slot_out) {
  constexpr int W = H;
  constexpr int KT = (K3 ? 9 : 1) * CI;
  constexpr int SLABS = (KT + 31) / 32;
  constexpr int KP = SLABS * 32;
  constexpr int COT = CO / (16 * CSPLIT);
  constexpr int HO = POOL ? H / 2 : H;
  constexpr int WO = POOL ? W / 2 : W;

  const int lane = threadIdx.x & 63, widx = threadIdx.x >> 6;
  const int quad = lane >> 4, col = lane & 15;
  const float s_in = p2_scale_f(slot_in[0], 255.0f);
  const float inv = p2_inv(s_in);
  const float S = __fmul_rn(s_in, wslotp[0]);
  const int wv = blockIdx.x * 4 + widx;
  const int mt = wv / CSPLIT, ct = wv % CSPLIT;

  int n, h, w, ph = 0, pw = 0;
  if constexpr (POOL) {
    constexpr int PB = (HO / 2) * (WO / 2);
    n = wv / PB; int r = wv % PB;
    ph = r / (WO / 2); pw = r % (WO / 2);
    h = 4 * ph + (col >> 2); w = 4 * pw + (col & 3);
  } else {
    int p = mt * 16 + col;
    n = p / (H * W); int r = p % (H * W);
    h = r / W; w = r % W;
  }
  const float* ibase = in + (size_t)n * H * W * CI;

  float4 fa[SLABS], fb[SLABS];
  bool vm[SLABS];
  #pragma unroll
  for (int slab = 0; slab < SLABS; slab++) {
    const int kbase = slab * 32 + quad * 8;
    const float* ap;
    if constexpr (K3) {
      const int khkw = min(kbase / CI, 8);
      const int cib = kbase % CI;
      const int kh = khkw / 3, kw = khkw - kh * 3;
      const int hh = h + kh - 1, ww = w + kw - 1;
      vm[slab] = (hh >= 0) && (hh < H) && (ww >= 0) && (ww < W);
      const int hc = min(max(hh, 0), H - 1), wc = min(max(ww, 0), W - 1);
      ap = ibase + (size_t)(hc * W + wc) * CI + cib;
    } else {
      vm[slab] = true;
      ap = ibase + (size_t)(h * W + w) * CI + (kbase % CI);
    }
    fa[slab] = ((const float4*)ap)[0];
    fb[slab] = ((const float4*)ap)[1];
  }

  v4f acc[COT];
  #pragma unroll
  for (int c = 0; c < COT; c++) acc[c] = (v4f){0.f, 0.f, 0.f, 0.f};

  #pragma unroll
  for (int slab = 0; slab < SLABS; slab++) {
    const int kbase = slab * 32 + quad * 8;
    float ff[8] = {fa[slab].x, fa[slab].y, fa[slab].z, fa[slab].w,
                   fb[slab].x, fb[slab].y, fb[slab].z, fb[slab].w};
    v8s a;
    #pragma unroll
    for (int j = 0; j < 8; j++) {
      float q = rintf(__fmul_rn(ff[j], inv));
      a[j] = vm[slab] ? ibf16(q) : (short)0;
    }
    #pragma unroll
    for (int c = 0; c < COT; c++) {
      v8s b = *(const v8s*)(wt + (size_t)((ct * COT + c) * 16 + col) * KP + kbase);
      acc[c] = __builtin_amdgcn_mfma_f32_16x16x32_bf16(a, b, acc[c], 0, 0, 0);
    }
  }

  float zmax = 0.f;
  #pragma unroll
  for (int c = 0; c < COT; c++) {
    const int cog = (ct * COT + c) * 16 + col;
    const float g = sg[cog], bb = sb[cog];
    float z[4];
    #pragma unroll
    for (int r2 = 0; r2 < 4; r2++) {
      float t = __fmul_rn(acc[c][r2], S);
      z[r2] = fmaxf(__fadd_rn(__fmul_rn(t, g), bb), 0.f);
    }
    if constexpr (POOL) {
      float h0 = fmaxf(z[0], z[1]), h1 = fmaxf(z[2], z[3]);
      float o0 = fmaxf(h0, __shfl_xor(h0, 16));
      float o1 = fmaxf(h1, __shfl_xor(h1, 16));
      zmax = fmaxf(zmax, fmaxf(o0, o1));
      if (!(quad & 1)) {
        int oh = 2 * ph + (quad >> 1), ow = 2 * pw;
        float* op = out + ((size_t)((n * HO + oh) * WO + ow)) * CO + cog;
        op[0] = o0; op[CO] = o1;
      }
    } else {
      const int pbase = mt * 16 + quad * 4;
      #pragma unroll
      for (int r2 = 0; r2 < 4; r2++) {
        out[(size_t)(pbase + r2) * CO + cog] = z[r2];
        zmax = fmaxf(zmax, z[r2]);
      }
    }
  }
  wave_max_update(zmax, slot_out);
}

// NHWC avgpool: in [16][784][64] raw; quantize on read, exact sum, one divide.
__global__ void avgpool_kernel(const float* __restrict__ in, float* __restrict__ out,
                               const float* __restrict__ slot_in, float* slot_out) {
  __shared__ float red[1024];
  const float s = p2_scale_f(slot_in[0], 255.0f);
  const float inv = p2_inv(s);
  const int nn = blockIdx.x, co = threadIdx.x & 63, part = threadIdx.x >> 6;
  const float* p = in + (size_t)nn * 784 * 64;
  float sum = 0.f;
  for (int i = part * 49; i < part * 49 + 49; i++)
    sum += __fmul_rn(rintf(__fmul_rn(p[i * 64 + co], inv)), s);
  red[threadIdx.x] = sum;
  __syncthreads();
  if (threadIdx.x < 64) {
    float tot = 0.f;
    #pragma unroll
    for (int k2 = 0; k2 < 16; k2++) tot += red[k2 * 64 + co];
    float m = __fdiv_rn(tot, 784.0f);
    out[nn * 64 + co] = m;
    slot_max_update(slot_out, m);
  }
}

// quant(mean) -> fc1 -> relu -> quant -> fc2, one 256-thread block.
__global__ void tail_kernel(const float* __restrict__ pooled,
                            const float* __restrict__ fw1, const float* __restrict__ fb1,
                            const float* __restrict__ fw2, const float* __restrict__ fb2,
                            const float* __restrict__ slot_in, float* __restrict__ out) {
  __shared__ float xq[1024];
  __shared__ float hq[256];
  __shared__ float s2s;
  const int t = threadIdx.x;
  const float s = p2_scale_f(slot_in[0], 255.0f);
  const float inv = p2_inv(s);
  for (int i = t; i < 1024; i += 256)
    xq[i] = __fmul_rn(rintf(__fmul_rn(pooled[i], inv)), s);
  __syncthreads();
  const int n = t >> 4, j = t & 15;
  float acc = 0.f;
  #pragma unroll 8
  for (int k = 0; k < 64; k++) acc += xq[n * 64 + k] * fw1[k * 16 + j];  // exact
  float z = fmaxf(__fadd_rn(acc, fb1[j]), 0.f);
  float bm = block_reduce_max256(z);
  if (t == 0) s2s = p2_scale_f(bm, 255.0f);
  __syncthreads();
  const float s2 = s2s, inv2 = p2_inv(s2);
  hq[t] = __fmul_rn(rintf(__fmul_rn(z, inv2)), s2);
  __syncthreads();
  if (t < 160) {
    const int n2 = t / 10, j2 = t % 10;
    float a2 = 0.f;
    #pragma unroll
    for (int k = 0; k < 16; k++) a2 += hq[n2 * 16 + k] * fw2[k * 10 + j2];  // exact
    out[t] = __fadd_rn(a2, fb2[j2]);
  }
}

extern "C" void kernel_launch(void* const* d_in, const int* in_sizes, int n_in,
                              void* d_out, int out_size, void* d_ws, size_t ws_size,
                              hipStream_t stream) {
  static const int h_ci[NL] = {3, 32, 16, 16, 32, 32, 64, 32, 64, 32, 64, 32};
  static const int h_co[NL] = {32, 16, 16, 32, 32, 64, 32, 64, 32, 64, 32, 64};
  static const int h_kk[NL] = {9, 9, 1, 9, 1, 9, 1, 9, 1, 9, 1, 9};
  static const int h_kp[NL] = {64, 288, 32, 160, 32, 288, 64, 288, 64, 288, 64, 288};

  float* ws = (float*)d_ws;
  float* slots = ws;                 // [0..13] activation-max slots
  float* wslot = ws + 16;            // [0..11] conv weight scales
  size_t off = 32;

  short* wq[NL];
  for (int l = 0; l < NL; l++) {
    wq[l] = (short*)(ws + off);
    off += (size_t)(h_co[l] * h_kp[l] + 1) / 2;   // shorts -> floats
  }
  float* sgq[NL]; float* sbq[NL];
  for (int l = 0; l < NL; l++) { sgq[l] = ws + off; off += 64; }
  for (int l = 0; l < NL; l++) { sbq[l] = ws + off; off += 64; }
  float* fw1q = ws + off; off += 1024;
  float* fb1q = ws + off; off += 16;
  float* fw2q = ws + off; off += 160;
  float* fb2q = ws + off; off += 16;
  float* A = ws + off; off += 6422528;   // NHWC ping (max: conv1 out 25.7 MB)
  float* B = ws + off; off += 1605632;   // NHWC pong (max: conv32 out 6.4 MB)
  float* P = ws + off; off += 1024;      // pooled means [16][64]

  PrepArgs pa;
  for (int l = 0; l < NL; l++) {
    pa.in[l] = (const float*)d_in[1 + 3 * l]; pa.out[l] = (void*)wq[l];
    pa.n[l] = h_co[l] * h_ci[l] * h_kk[l];
    pa.mode[l] = (l == 0) ? 3 : 2; pa.tc[l] = 0;
    pa.ci[l] = h_ci[l]; pa.kk[l] = h_kk[l]; pa.kp[l] = h_kp[l]; pa.co[l] = h_co[l];
    pa.in[12 + l] = (const float*)d_in[2 + 3 * l]; pa.out[12 + l] = (void*)sgq[l];
    pa.n[12 + l] = h_co[l]; pa.mode[12 + l] = 0; pa.tc[12 + l] = 0;
    pa.ci[12 + l] = pa.kk[12 + l] = pa.kp[12 + l] = pa.co[12 + l] = 0;
    pa.in[24 + l] = (const float*)d_in[3 + 3 * l]; pa.out[24 + l] = (void*)sbq[l];
    pa.n[24 + l] = h_co[l]; pa.mode[24 + l] = 0; pa.tc[24 + l] = 0;
    pa.ci[24 + l] = pa.kk[24 + l] = pa.kp[24 + l] = pa.co[24 + l] = 0;
  }
  pa.in[36] = (const float*)d_in[37]; pa.out[36] = (void*)fw1q;
  pa.n[36] = 1024; pa.mode[36] = 1; pa.tc[36] = 16;
  pa.ci[36] = pa.kk[36] = pa.kp[36] = pa.co[36] = 0;
  pa.in[37] = (const float*)d_in[38]; pa.out[37] = (void*)fb1q;
  pa.n[37] = 16; pa.mode[37] = 0; pa.tc[37] = 0;
  pa.ci[37] = pa.kk[37] = pa.kp[37] = pa.co[37] = 0;
  pa.in[38] = (const float*)d_in[39]; pa.out[38] = (void*)fw2q;
  pa.n[38] = 160; pa.mode[38] = 1; pa.tc[38] = 10;
  pa.ci[38] = pa.kk[38] = pa.kp[38] = pa.co[38] = 0;
  pa.in[39] = (const float*)d_in[40]; pa.out[39] = (void*)fb2q;
  pa.n[39] = 10; pa.mode[39] = 0; pa.tc[39] = 0;
  pa.ci[39] = pa.kk[39] = pa.kp[39] = pa.co[39] = 0;

  const float* x = (const float*)d_in[0];
  const int nx = 16 * 3 * 224 * 224;

  hipMemsetAsync(slots, 0, 16 * sizeof(float), stream);
  prep_kernel<<<40 + 294, 256, 0, stream>>>(pa, wslot, x, nx, slots + 0);

  conv1_lds<<<16 * 7 * 7, 256, 0, stream>>>(x, wq[0], sgq[0], sbq[0], A,
                                            slots + 0, wslot + 0, slots + 1);
  conv_lds<32, 112, 16, true, 16><<<16 * 49, 256, 0, stream>>>(
      A, wq[1], sgq[1], sbq[1], B, slots + 1, wslot + 1, slots + 2);
  conv_mfma<16, 56, 16, false, false, 1><<<784, 256, 0, stream>>>(
      B, wq[2], sgq[2], sbq[2], A, slots + 2, wslot + 2, slots + 3);
  conv_lds<16, 56, 32, false, 16><<<16 * 16, 256, 0, stream>>>(
      A, wq[3], sgq[3], sbq[3], B, slots + 3, wslot + 3, slots + 4);
  conv_mfma<32, 56, 32, false, false, 2><<<1568, 256, 0, stream>>>(
      B, wq[4], sgq[4], sbq[4], A, slots + 4, wslot + 4, slots + 5);
  conv_lds<32, 56, 64, true, 16><<<16 * 16, 256, 0, stream>>>(
      A, wq[5], sgq[5], sbq[5], B, slots + 5, wslot + 5, slots + 6);
  conv_mfma<64, 28, 32, false, false, 2><<<392, 256, 0, stream>>>(
      B, wq[6], sgq[6], sbq[6], A, slots + 6, wslot + 6, slots + 7);
  conv_lds<32, 28, 64, false, 8><<<16 * 16, 256, 0, stream>>>(
      A, wq[7], sgq[7], sbq[7], B, slots + 7, wslot + 7, slots + 8);
  conv_mfma<64, 28, 32, false, false, 2><<<392, 256, 0, stream>>>(
      B, wq[8], sgq[8], sbq[8], A, slots + 8, wslot + 8, slots + 9);
  conv_lds<32, 28, 64, false, 8><<<16 * 16, 256, 0, stream>>>(
      A, wq[9], sgq[9], sbq[9], B, slots + 9, wslot + 9, slots + 10);
  conv_mfma<64, 28, 32, false, false, 2><<<392, 256, 0, stream>>>(
      B, wq[10], sgq[10], sbq[10], A, slots + 10, wslot + 10, slots + 11);
  conv_lds<32, 28, 64, false, 8><<<16 * 16, 256, 0, stream>>>(
      A, wq[11], sgq[11], sbq[11], B, slots + 11, wslot + 11, slots + 12);

  avgpool_kernel<<<16, 1024, 0, stream>>>(B, P, slots + 12, slots + 13);
  tail_kernel<<<1, 256, 0, stream>>>(P, fw1q, fb1q, fw2q, fb2q, slots + 13,
                                     (float*)d_out);
}

// Round 8
// 327.842 us; speedup vs baseline: 1.5321x; 1.5321x over previous
//
#include <hip/hip_runtime.h>
#include <math.h>

#define NL 12

typedef short v8s __attribute__((ext_vector_type(8)));
typedef float v4f __attribute__((ext_vector_type(4)));

struct PrepArgs {
  const float* in[40];
  void* out[40];
  int n[40];      // input element count
  int mode[40];   // 0 plain f32, 1 transposed f32, 2 conv int-bf16, 3 conv1 CI3->4 pad
  int tc[40];     // mode1: minor dim
  int ci[40], kk[40], kp[40], co[40];   // mode2/3 geometry
};

// power-of-two scale: 2^ceil(log2(max(maxv,1e-8)/levels)).
// Bit-exact: for positive normal r, ceil(log2(r)) = (e-127) + (mantissa!=0).
__device__ inline float p2_scale_f(float maxv, float levels) {
  float r = __fdiv_rn(fmaxf(maxv, 1e-8f), levels);
  unsigned b = __float_as_uint(r);
  unsigned e = (b >> 23) & 0xffu;
  e += (b & 0x7fffffu) ? 1u : 0u;
  return __uint_as_float(e << 23);
}

// exact reciprocal of a power-of-two scale: 2^-k from 2^k by exponent flip
__device__ inline float p2_inv(float s) {
  return __uint_as_float((254u << 23) - __float_as_uint(s));
}

// blockDim must be 256. Result valid on thread 0. All threads must reach.
__device__ inline float block_reduce_max256(float v) {
  __shared__ float sm[4];
  #pragma unroll
  for (int off = 32; off; off >>= 1) v = fmaxf(v, __shfl_down(v, off));
  if ((threadIdx.x & 63) == 0) sm[threadIdx.x >> 6] = v;
  __syncthreads();
  if (threadIdx.x == 0) v = fmaxf(fmaxf(sm[0], sm[1]), fmaxf(sm[2], sm[3]));
  return v;
}

// v >= 0; non-negative float bits compare like unsigned. Read-skip cuts atomics.
// ONE guarded atomic per BLOCK only (R7 lesson: per-wave atomics on one
// device-scope address cross-XCD serialized -> conv_mfma 42 -> 110 us).
__device__ inline void slot_max_update(float* slot, float v) {
  volatile unsigned int* su = (volatile unsigned int*)slot;
  unsigned int bits = __float_as_uint(v);
  if (bits > *su) atomicMax((unsigned int*)slot, bits);
}

// integer-valued float -> bf16 bits by truncation (exact for |v| <= 256)
__device__ inline short ibf16(float v) {
  return (short)(__float_as_uint(v) >> 16);
}

// blocks [0,40): per-tensor weight prep. blocks >=40: grid-stride max of x.
__global__ void prep_kernel(PrepArgs a, float* wslot,
                            const float* __restrict__ x, int nx, float* slot0) {
  if (blockIdx.x >= 40) {
    const float4* xv = (const float4*)x;
    const int nv = nx >> 2;
    float m0 = 0.f, m1 = 0.f, m2 = 0.f, m3 = 0.f;
    for (int i = (blockIdx.x - 40) * 256 + threadIdx.x; i < nv;
         i += (gridDim.x - 40) * 256) {
      float4 v = xv[i];
      m0 = fmaxf(m0, v.x); m1 = fmaxf(m1, v.y);
      m2 = fmaxf(m2, v.z); m3 = fmaxf(m3, v.w);
    }
    float m = fmaxf(fmaxf(m0, m1), fmaxf(m2, m3));
    float bm = block_reduce_max256(m);
    if (threadIdx.x == 0) slot_max_update(slot0, bm);
    return;
  }
  __shared__ float ssc;
  const int t = blockIdx.x;
  const float* in = a.in[t];
  const int n = a.n[t], mode = a.mode[t];
  float m = 0.f;
  if (mode >= 2) {
    const float4* in4 = (const float4*)in;
    const int n4 = n >> 2;
    for (int i = threadIdx.x; i < n4; i += 256) {
      float4 v = in4[i];
      m = fmaxf(m, fmaxf(fmaxf(fabsf(v.x), fabsf(v.y)),
                         fmaxf(fabsf(v.z), fabsf(v.w))));
    }
  } else {
    for (int i = threadIdx.x; i < n; i += 256) m = fmaxf(m, fabsf(in[i]));
  }
  float bm = block_reduce_max256(m);
  if (threadIdx.x == 0) {
    ssc = p2_scale_f(bm, 127.0f);
    if (mode >= 2) wslot[t] = ssc;
  }
  __syncthreads();
  const float s = ssc;
  if (mode == 3) {
    // conv1 weight: layout [32][64], k = khkw*4 + ci (CI padded 3->4);
    // zero for ci==3, khkw>=9 -> kernel needs no k-mask.
    ushort* o = (ushort*)a.out[t];
    for (int i = threadIdx.x; i < 32 * 64; i += 256) {
      int co = i >> 6, k = i & 63;
      int khkw = k >> 2, ci = k & 3;
      ushort v = 0;
      if (khkw < 9 && ci < 3) {
        float q = rintf(__fdiv_rn(in[(co * 3 + ci) * 9 + khkw], s));
        q = fminf(fmaxf(q, -128.f), 127.f);
        v = (ushort)(__float_as_uint(q) >> 16);
      }
      o[i] = v;
    }
  } else if (mode == 2) {
    // conv weight: int codes as bf16, layout [Co][KP], k = khkw*Ci + ci, zero pad
    ushort* o = (ushort*)a.out[t];
    const int CI = a.ci[t], KK = a.kk[t], KP = a.kp[t], CO = a.co[t];
    const int KT = CI * KK;
    for (int i = threadIdx.x; i < CO * KP; i += 256) {
      int co = i / KP, k = i % KP;
      ushort v = 0;
      if (k < KT) {
        int khkw = k / CI, ci = k % CI;
        float q = rintf(__fdiv_rn(in[(co * CI + ci) * KK + khkw], s));
        q = fminf(fmaxf(q, -128.f), 127.f);
        v = (ushort)(__float_as_uint(q) >> 16);   // exact: |q| <= 128
      }
      o[i] = v;
    }
  } else {
    float* o = (float*)a.out[t];
    const int tc = a.tc[t];
    const int nw = (mode == 1) ? n / tc : 1;
    for (int i = threadIdx.x; i < n; i += 256) {
      float q = rintf(__fdiv_rn(in[i], s));
      q = fminf(fmaxf(q, -128.f), 127.f);
      float v = __fmul_rn(q, s);
      if (mode == 1) o[(i % nw) * tc + i / nw] = v;
      else o[i] = v;
    }
  }
}

// ---------- LDS-staged MFMA conv for K3 layers ----------
// Each block stages a contiguous TINxTIN NHWC tile with coalesced float4
// loads (quantizing ONCE per pixel) into LDS, then MFMA A-fragments come from
// ds_read_b128. Halo / out-of-image pixels are code 0 (= conv zero padding).
// Ragged edge tiles: stores and zmax are validity-guarded.
// CI=32 LDS layout: 8-short channel blocks XOR-rotated by ((p&3)<<3).

template <int CI, int H, int CO, bool POOL, int TOUT>
__global__ __launch_bounds__(256)
void conv_lds(const float* __restrict__ in, const short* __restrict__ wt,
              const float* __restrict__ sg, const float* __restrict__ sb,
              float* __restrict__ out, const float* __restrict__ slot_in,
              const float* __restrict__ wslotp, float* slot_out) {
  constexpr int W = H;
  constexpr int KT = 9 * CI;
  constexpr int SLABS = (KT + 31) / 32;
  constexpr int KP = SLABS * 32;
  constexpr int COT = CO / 16;
  constexpr int TIN = TOUT + 2;
  constexpr int NTL = (H + TOUT - 1) / TOUT;
  constexpr int PT = TOUT / 4;
  constexpr int NP = (PT * PT) / 4;     // patches per wave
  constexpr int HO = POOL ? H / 2 : H;
  constexpr int WO = POOL ? W / 2 : W;
  constexpr int LG = (CI == 16) ? 2 : 3;   // log2(CI/4)
  constexpr int CH = CI / 4;

  __shared__ ushort lds[TIN * TIN * CI];

  auto lidx = [](int pix, int cs) -> int {   // cs: short offset, multiple of 4
    if constexpr (CI == 32) return pix * CI + (cs ^ ((pix & 3) << 3));
    else return pix * CI + cs;
  };

  const int lane = threadIdx.x & 63, widx = threadIdx.x >> 6;
  const int quad = lane >> 4, col = lane & 15;
  const float s_in = p2_scale_f(slot_in[0], 255.0f);
  const float inv = p2_inv(s_in);
  const float S = __fmul_rn(s_in, wslotp[0]);

  const int bt = blockIdx.x;
  const int n = bt / (NTL * NTL);
  const int rr = bt % (NTL * NTL);
  const int ty = rr / NTL, tx = rr % NTL;
  const int gh0 = ty * TOUT - 1, gw0 = tx * TOUT - 1;
  const float* ib = in + (size_t)n * H * W * CI;

  for (int i = threadIdx.x; i < TIN * TIN * CH; i += 256) {
    const int pix = i >> LG, cg = i & (CH - 1);
    const int hi = pix / TIN, wi = pix - hi * TIN;
    const int gh = gh0 + hi, gw = gw0 + wi;
    float4 f = {0.f, 0.f, 0.f, 0.f};
    if ((unsigned)gh < (unsigned)H && (unsigned)gw < (unsigned)W)
      f = *(const float4*)(ib + ((size_t)(gh * W + gw)) * CI + cg * 4);
    ushort4 c;
    c.x = (ushort)ibf16(rintf(__fmul_rn(f.x, inv)));
    c.y = (ushort)ibf16(rintf(__fmul_rn(f.y, inv)));
    c.z = (ushort)ibf16(rintf(__fmul_rn(f.z, inv)));
    c.w = (ushort)ibf16(rintf(__fmul_rn(f.w, inv)));
    *(ushort4*)(lds + lidx(pix, cg * 4)) = c;
  }
  __syncthreads();

  v4f acc[NP][COT];
  #pragma unroll
  for (int p = 0; p < NP; p++)
    #pragma unroll
    for (int c = 0; c < COT; c++) acc[p][c] = (v4f){0.f, 0.f, 0.f, 0.f};

  #pragma unroll
  for (int slab = 0; slab < SLABS; slab++) {
    const int kbase = slab * 32 + quad * 8;
    int tap = kbase / CI; tap = min(tap, 8);
    const int cib = kbase % CI;
    const int kh = tap / 3, kw = tap - kh * 3;
    v8s b[COT];
    #pragma unroll
    for (int c = 0; c < COT; c++)
      b[c] = *(const v8s*)(wt + (size_t)(c * 16 + col) * KP + kbase);
    #pragma unroll
    for (int p = 0; p < NP; p++) {
      const int q = widx * NP + p;
      const int plh = (q / PT) * 4, plw = (q % PT) * 4;
      const int hin = plh + (col >> 2) + kh, win = plw + (col & 3) + kw;
      v8s a = *(const v8s*)(lds + lidx(hin * TIN + win, cib));
      #pragma unroll
      for (int c = 0; c < COT; c++)
        acc[p][c] = __builtin_amdgcn_mfma_f32_16x16x32_bf16(a, b[c], acc[p][c], 0, 0, 0);
    }
  }

  float zmax = 0.f;
  #pragma unroll
  for (int p = 0; p < NP; p++) {
    const int q = widx * NP + p;
    const int plh = (q / PT) * 4, plw = (q % PT) * 4;
    const int gho = ty * TOUT + plh, gwo = tx * TOUT + plw;
    #pragma unroll
    for (int c = 0; c < COT; c++) {
      const int cog = c * 16 + col;
      const float g = sg[cog], bb = sb[cog];
      float z[4];
      #pragma unroll
      for (int r2 = 0; r2 < 4; r2++) {
        float t = __fmul_rn(acc[p][c][r2], S);                  // exact
        z[r2] = fmaxf(__fadd_rn(__fmul_rn(t, g), bb), 0.f);     // matches XLA
      }
      if constexpr (POOL) {
        float h0 = fmaxf(z[0], z[1]), h1 = fmaxf(z[2], z[3]);
        float o0 = fmaxf(h0, __shfl_xor(h0, 16));
        float o1 = fmaxf(h1, __shfl_xor(h1, 16));
        const int oh = (gho >> 1) + (quad >> 1), ow = gwo >> 1;
        const bool v0 = (oh < HO) && (ow < WO), v1 = (oh < HO) && (ow + 1 < WO);
        zmax = fmaxf(zmax, fmaxf(v0 ? o0 : 0.f, v1 ? o1 : 0.f));
        if (!(quad & 1)) {
          float* op = out + ((size_t)((n * HO + oh) * WO + ow)) * CO + cog;
          if (v0) op[0] = o0;
          if (v1) op[CO] = o1;
        }
      } else {
        const int hh = gho + quad;
        #pragma unroll
        for (int r2 = 0; r2 < 4; r2++) {
          const int wwo = gwo + r2;
          if (hh < H && wwo < W) {
            out[(size_t)((n * H + hh) * W + wwo) * CO + cog] = z[r2];
            zmax = fmaxf(zmax, z[r2]);
          }
        }
      }
    }
  }
  float bm = block_reduce_max256(zmax);
  if (threadIdx.x == 0) slot_max_update(slot_out, bm);
}

// conv1, LDS-staged, TOUT=32 (224/32=7 exact, zero ragged): stages+quantizes
// directly from NCHW f32 x into a 34x34x4 code tile (9.2KB LDS). K-layout
// k = khkw*4+ci (KP=64, 2 slabs), weights zero for ci==3 / khkw>=9 so no
// k-mask. Per wave: 16 patches processed serially with acc[2] reused
// (low VGPR); weights hoisted once. CO=32, pool 224->112, NHWC f32 out.
__global__ __launch_bounds__(256)
void conv1_lds(const float* __restrict__ x, const short* __restrict__ wt,
               const float* __restrict__ sg, const float* __restrict__ sb,
               float* __restrict__ out, const float* __restrict__ slot_in,
               const float* __restrict__ wslotp, float* slot_out) {
  constexpr int H = 224, W = 224, CO = 32, TOUT = 32, TIN = 34, NTL = 7;
  constexpr int HO = 112, WO = 112;
  __shared__ ushort lds[TIN * TIN * 4];

  const int lane = threadIdx.x & 63, widx = threadIdx.x >> 6;
  const int quad = lane >> 4, col = lane & 15;
  const float s_in = p2_scale_f(slot_in[0], 255.0f);
  const float inv = p2_inv(s_in);
  const float S = __fmul_rn(s_in, wslotp[0]);

  const int bt = blockIdx.x;
  const int n = bt / (NTL * NTL);
  const int rr = bt % (NTL * NTL);
  const int ty = rr / NTL, tx = rr % NTL;
  const int gh0 = ty * TOUT - 1, gw0 = tx * TOUT - 1;
  const float* xb = x + (size_t)n * 3 * H * W;

  for (int i = threadIdx.x; i < 3 * TIN * TIN; i += 256) {
    const int c = i / (TIN * TIN), pix = i - c * (TIN * TIN);
    const int hi = pix / TIN, wi = pix - hi * TIN;
    const int gh = gh0 + hi, gw = gw0 + wi;
    ushort code = 0;
    if ((unsigned)gh < (unsigned)H && (unsigned)gw < (unsigned)W)
      code = (ushort)ibf16(rintf(__fmul_rn(xb[(size_t)c * H * W + gh * W + gw], inv)));
    lds[pix * 4 + c] = code;
  }
  for (int i = threadIdx.x; i < TIN * TIN; i += 256) lds[i * 4 + 3] = 0;
  __syncthreads();

  // hoisted weight fragments: bfr[slab][c], kbase = slab*32 + quad*8
  v8s bfr[2][2];
  #pragma unroll
  for (int slab = 0; slab < 2; slab++) {
    bfr[slab][0] = *(const v8s*)(wt + (size_t)(col) * 64 + slab * 32 + quad * 8);
    bfr[slab][1] = *(const v8s*)(wt + (size_t)(16 + col) * 64 + slab * 32 + quad * 8);
  }
  // taps per (slab, quad): {slab*8+quad*2, +1}, clamped to 8 (zero weights pair)
  const int t0A = min(quad * 2, 8),     t0B = min(quad * 2 + 1, 8);
  const int t1A = min(8 + quad * 2, 8), t1B = min(8 + quad * 2 + 1, 8);

  auto read4 = [&](int ph, int pw, int tap) -> ushort4 {
    const int hin = ph + (col >> 2) + tap / 3, win = pw + (col & 3) + tap % 3;
    return ((const ushort4*)lds)[hin * TIN + win];
  };
  auto mka = [](ushort4 lo, ushort4 hi) -> v8s {
    v8s a;
    a[0] = (short)lo.x; a[1] = (short)lo.y; a[2] = (short)lo.z; a[3] = (short)lo.w;
    a[4] = (short)hi.x; a[5] = (short)hi.y; a[6] = (short)hi.z; a[7] = (short)hi.w;
    return a;
  };

  float zmax = 0.f;
  for (int p = widx; p < 64; p += 4) {       // 8x8 grid of 4x4 patches
    const int plh = (p >> 3) * 4, plw = (p & 7) * 4;
    v4f acc[2];
    acc[0] = (v4f){0.f, 0.f, 0.f, 0.f}; acc[1] = acc[0];
    {
      v8s a = mka(read4(plh, plw, t0A), read4(plh, plw, t0B));
      acc[0] = __builtin_amdgcn_mfma_f32_16x16x32_bf16(a, bfr[0][0], acc[0], 0, 0, 0);
      acc[1] = __builtin_amdgcn_mfma_f32_16x16x32_bf16(a, bfr[0][1], acc[1], 0, 0, 0);
    }
    {
      v8s a = mka(read4(plh, plw, t1A), read4(plh, plw, t1B));
      acc[0] = __builtin_amdgcn_mfma_f32_16x16x32_bf16(a, bfr[1][0], acc[0], 0, 0, 0);
      acc[1] = __builtin_amdgcn_mfma_f32_16x16x32_bf16(a, bfr[1][1], acc[1], 0, 0, 0);
    }
    const int gho = ty * TOUT + plh, gwo = tx * TOUT + plw;
    #pragma unroll
    for (int c = 0; c < 2; c++) {
      const int cog = c * 16 + col;
      const float g = sg[cog], bb = sb[cog];
      float z[4];
      #pragma unroll
      for (int r2 = 0; r2 < 4; r2++) {
        float t = __fmul_rn(acc[c][r2], S);
        z[r2] = fmaxf(__fadd_rn(__fmul_rn(t, g), bb), 0.f);
      }
      float h0 = fmaxf(z[0], z[1]), h1 = fmaxf(z[2], z[3]);
      float o0 = fmaxf(h0, __shfl_xor(h0, 16));
      float o1 = fmaxf(h1, __shfl_xor(h1, 16));
      zmax = fmaxf(zmax, fmaxf(o0, o1));   // 224%32==0: always valid
      if (!(quad & 1)) {
        const int oh = (gho >> 1) + (quad >> 1), ow = gwo >> 1;
        float* op = out + ((size_t)((n * HO + oh) * WO + ow)) * CO + cog;
        op[0] = o0; op[CO] = o1;
      }
    }
  }
  float bm = block_reduce_max256(zmax);
  if (threadIdx.x == 0) slot_max_update(slot_out, bm);
}

// ---------- old implicit-GEMM conv, kept for K1 layers (dense gathers) ----------
template <int CI, int H, int CO, bool K3, bool POOL, int CSPLIT>
__global__ __launch_bounds__(256)
void conv_mfma(const float* __restrict__ in, const short* __restrict__ wt,
               const float* __restrict__ sg, const float* __restrict__ sb,
               float* __restrict__ out, const float* __restrict__ slot_in,
               const float* __restrict__ wslotp, float* slot_out) {
  constexpr int W = H;
  constexpr int KT = (K3 ? 9 : 1) * CI;
  constexpr int SLABS = (KT + 31) / 32;
  constexpr int KP = SLABS * 32;
  constexpr int COT = CO / (16 * CSPLIT);
  constexpr int HO = POOL ? H / 2 : H;
  constexpr int WO = POOL ? W / 2 : W;

  const int lane = threadIdx.x & 63, widx = threadIdx.x >> 6;
  const int quad = lane >> 4, col = lane & 15;
  const float s_in = p2_scale_f(slot_in[0], 255.0f);
  const float inv = p2_inv(s_in);
  const float S = __fmul_rn(s_in, wslotp[0]);
  const int wv = blockIdx.x * 4 + widx;
  const int mt = wv / CSPLIT, ct = wv % CSPLIT;

  int n, h, w, ph = 0, pw = 0;
  if constexpr (POOL) {
    constexpr int PB = (HO / 2) * (WO / 2);
    n = mt / PB; int r = mt % PB;
    ph = r / (WO / 2); pw = r % (WO / 2);
    h = 4 * ph + (col >> 2); w = 4 * pw + (col & 3);
  } else {
    int p = mt * 16 + col;
    n = p / (H * W); int r = p % (H * W);
    h = r / W; w = r % W;
  }
  const float* ibase = in + (size_t)n * H * W * CI;

  float4 fa[SLABS], fb[SLABS];
  bool vm[SLABS];
  #pragma unroll
  for (int slab = 0; slab < SLABS; slab++) {
    const int kbase = slab * 32 + quad * 8;
    const float* ap;
    if constexpr (K3) {
      const int khkw = min(kbase / CI, 8);
      const int cib = kbase % CI;
      const int kh = khkw / 3, kw = khkw - kh * 3;
      const int hh = h + kh - 1, ww = w + kw - 1;
      vm[slab] = (hh >= 0) && (hh < H) && (ww >= 0) && (ww < W);
      const int hc = min(max(hh, 0), H - 1), wc = min(max(ww, 0), W - 1);
      ap = ibase + (size_t)(hc * W + wc) * CI + cib;
    } else {
      vm[slab] = true;
      ap = ibase + (size_t)(h * W + w) * CI + (kbase % CI);
    }
    fa[slab] = ((const float4*)ap)[0];
    fb[slab] = ((const float4*)ap)[1];
  }

  v4f acc[COT];
  #pragma unroll
  for (int c = 0; c < COT; c++) acc[c] = (v4f){0.f, 0.f, 0.f, 0.f};

  #pragma unroll
  for (int slab = 0; slab < SLABS; slab++) {
    const int kbase = slab * 32 + quad * 8;
    float ff[8] = {fa[slab].x, fa[slab].y, fa[slab].z, fa[slab].w,
                   fb[slab].x, fb[slab].y, fb[slab].z, fb[slab].w};
    v8s a;
    #pragma unroll
    for (int j = 0; j < 8; j++) {
      float q = rintf(__fmul_rn(ff[j], inv));
      a[j] = vm[slab] ? ibf16(q) : (short)0;
    }
    #pragma unroll
    for (int c = 0; c < COT; c++) {
      v8s b = *(const v8s*)(wt + (size_t)((ct * COT + c) * 16 + col) * KP + kbase);
      acc[c] = __builtin_amdgcn_mfma_f32_16x16x32_bf16(a, b, acc[c], 0, 0, 0);
    }
  }

  float zmax = 0.f;
  #pragma unroll
  for (int c = 0; c < COT; c++) {
    const int cog = (ct * COT + c) * 16 + col;
    const float g = sg[cog], bb = sb[cog];
    float z[4];
    #pragma unroll
    for (int r2 = 0; r2 < 4; r2++) {
      float t = __fmul_rn(acc[c][r2], S);
      z[r2] = fmaxf(__fadd_rn(__fmul_rn(t, g), bb), 0.f);
    }
    if constexpr (POOL) {
      float h0 = fmaxf(z[0], z[1]), h1 = fmaxf(z[2], z[3]);
      float o0 = fmaxf(h0, __shfl_xor(h0, 16));
      float o1 = fmaxf(h1, __shfl_xor(h1, 16));
      zmax = fmaxf(zmax, fmaxf(o0, o1));
      if (!(quad & 1)) {
        int oh = 2 * ph + (quad >> 1), ow = 2 * pw;
        float* op = out + ((size_t)((n * HO + oh) * WO + ow)) * CO + cog;
        op[0] = o0; op[CO] = o1;
      }
    } else {
      const int pbase = mt * 16 + quad * 4;
      #pragma unroll
      for (int r2 = 0; r2 < 4; r2++) {
        out[(size_t)(pbase + r2) * CO + cog] = z[r2];
        zmax = fmaxf(zmax, z[r2]);
      }
    }
  }
  float bm = block_reduce_max256(zmax);
  if (threadIdx.x == 0) slot_max_update(slot_out, bm);
}

// NHWC avgpool: in [16][784][64] raw; quantize on read, exact sum, one divide.
__global__ void avgpool_kernel(const float* __restrict__ in, float* __restrict__ out,
                               const float* __restrict__ slot_in, float* slot_out) {
  __shared__ float red[1024];
  const float s = p2_scale_f(slot_in[0], 255.0f);
  const float inv = p2_inv(s);
  const int nn = blockIdx.x, co = threadIdx.x & 63, part = threadIdx.x >> 6;
  const float* p = in + (size_t)nn * 784 * 64;
  float sum = 0.f;
  for (int i = part * 49; i < part * 49 + 49; i++)
    sum += __fmul_rn(rintf(__fmul_rn(p[i * 64 + co], inv)), s);
  red[threadIdx.x] = sum;
  __syncthreads();
  if (threadIdx.x < 64) {
    float tot = 0.f;
    #pragma unroll
    for (int k2 = 0; k2 < 16; k2++) tot += red[k2 * 64 + co];
    float m = __fdiv_rn(tot, 784.0f);
    out[nn * 64 + co] = m;
    slot_max_update(slot_out, m);
  }
}

// quant(mean) -> fc1 -> relu -> quant -> fc2, one 256-thread block.
__global__ void tail_kernel(const float* __restrict__ pooled,
                            const float* __restrict__ fw1, const float* __restrict__ fb1,
                            const float* __restrict__ fw2, const float* __restrict__ fb2,
                            const float* __restrict__ slot_in, float* __restrict__ out) {
  __shared__ float xq[1024];
  __shared__ float hq[256];
  __shared__ float s2s;
  const int t = threadIdx.x;
  const float s = p2_scale_f(slot_in[0], 255.0f);
  const float inv = p2_inv(s);
  for (int i = t; i < 1024; i += 256)
    xq[i] = __fmul_rn(rintf(__fmul_rn(pooled[i], inv)), s);
  __syncthreads();
  const int n = t >> 4, j = t & 15;
  float acc = 0.f;
  #pragma unroll 8
  for (int k = 0; k < 64; k++) acc += xq[n * 64 + k] * fw1[k * 16 + j];  // exact
  float z = fmaxf(__fadd_rn(acc, fb1[j]), 0.f);
  float bm = block_reduce_max256(z);
  if (t == 0) s2s = p2_scale_f(bm, 255.0f);
  __syncthreads();
  const float s2 = s2s, inv2 = p2_inv(s2);
  hq[t] = __fmul_rn(rintf(__fmul_rn(z, inv2)), s2);
  __syncthreads();
  if (t < 160) {
    const int n2 = t / 10, j2 = t % 10;
    float a2 = 0.f;
    #pragma unroll
    for (int k = 0; k < 16; k++) a2 += hq[n2 * 16 + k] * fw2[k * 10 + j2];  // exact
    out[t] = __fadd_rn(a2, fb2[j2]);
  }
}

extern "C" void kernel_launch(void* const* d_in, const int* in_sizes, int n_in,
                              void* d_out, int out_size, void* d_ws, size_t ws_size,
                              hipStream_t stream) {
  static const int h_ci[NL] = {3, 32, 16, 16, 32, 32, 64, 32, 64, 32, 64, 32};
  static const int h_co[NL] = {32, 16, 16, 32, 32, 64, 32, 64, 32, 64, 32, 64};
  static const int h_kk[NL] = {9, 9, 1, 9, 1, 9, 1, 9, 1, 9, 1, 9};
  static const int h_kp[NL] = {64, 288, 32, 160, 32, 288, 64, 288, 64, 288, 64, 288};

  float* ws = (float*)d_ws;
  float* slots = ws;                 // [0..13] activation-max slots
  float* wslot = ws + 16;            // [0..11] conv weight scales
  size_t off = 32;

  short* wq[NL];
  for (int l = 0; l < NL; l++) {
    wq[l] = (short*)(ws + off);
    off += (size_t)(h_co[l] * h_kp[l] + 1) / 2;   // shorts -> floats
  }
  float* sgq[NL]; float* sbq[NL];
  for (int l = 0; l < NL; l++) { sgq[l] = ws + off; off += 64; }
  for (int l = 0; l < NL; l++) { sbq[l] = ws + off; off += 64; }
  float* fw1q = ws + off; off += 1024;
  float* fb1q = ws + off; off += 16;
  float* fw2q = ws + off; off += 160;
  float* fb2q = ws + off; off += 16;
  float* A = ws + off; off += 6422528;   // NHWC ping (max: conv1 out 25.7 MB)
  float* B = ws + off; off += 1605632;   // NHWC pong (max: conv32 out 6.4 MB)
  float* P = ws + off; off += 1024;      // pooled means [16][64]

  PrepArgs pa;
  for (int l = 0; l < NL; l++) {
    pa.in[l] = (const float*)d_in[1 + 3 * l]; pa.out[l] = (void*)wq[l];
    pa.n[l] = h_co[l] * h_ci[l] * h_kk[l];
    pa.mode[l] = (l == 0) ? 3 : 2; pa.tc[l] = 0;
    pa.ci[l] = h_ci[l]; pa.kk[l] = h_kk[l]; pa.kp[l] = h_kp[l]; pa.co[l] = h_co[l];
    pa.in[12 + l] = (const float*)d_in[2 + 3 * l]; pa.out[12 + l] = (void*)sgq[l];
    pa.n[12 + l] = h_co[l]; pa.mode[12 + l] = 0; pa.tc[12 + l] = 0;
    pa.ci[12 + l] = pa.kk[12 + l] = pa.kp[12 + l] = pa.co[12 + l] = 0;
    pa.in[24 + l] = (const float*)d_in[3 + 3 * l]; pa.out[24 + l] = (void*)sbq[l];
    pa.n[24 + l] = h_co[l]; pa.mode[24 + l] = 0; pa.tc[24 + l] = 0;
    pa.ci[24 + l] = pa.kk[24 + l] = pa.kp[24 + l] = pa.co[24 + l] = 0;
  }
  pa.in[36] = (const float*)d_in[37]; pa.out[36] = (void*)fw1q;
  pa.n[36] = 1024; pa.mode[36] = 1; pa.tc[36] = 16;
  pa.ci[36] = pa.kk[36] = pa.kp[36] = pa.co[36] = 0;
  pa.in[37] = (const float*)d_in[38]; pa.out[37] = (void*)fb1q;
  pa.n[37] = 16; pa.mode[37] = 0; pa.tc[37] = 0;
  pa.ci[37] = pa.kk[37] = pa.kp[37] = pa.co[37] = 0;
  pa.in[38] = (const float*)d_in[39]; pa.out[38] = (void*)fw2q;
  pa.n[38] = 160; pa.mode[38] = 1; pa.tc[38] = 10;
  pa.ci[38] = pa.kk[38] = pa.kp[38] = pa.co[38] = 0;
  pa.in[39] = (const float*)d_in[40]; pa.out[39] = (void*)fb2q;
  pa.n[39] = 10; pa.mode[39] = 0; pa.tc[39] = 0;
  pa.ci[39] = pa.kk[39] = pa.kp[39] = pa.co[39] = 0;

  const float* x = (const float*)d_in[0];
  const int nx = 16 * 3 * 224 * 224;

  hipMemsetAsync(slots, 0, 16 * sizeof(float), stream);
  prep_kernel<<<40 + 294, 256, 0, stream>>>(pa, wslot, x, nx, slots + 0);

  conv1_lds<<<16 * 7 * 7, 256, 0, stream>>>(x, wq[0], sgq[0], sbq[0], A,
                                            slots + 0, wslot + 0, slots + 1);
  conv_lds<32, 112, 16, true, 16><<<16 * 49, 256, 0, stream>>>(
      A, wq[1], sgq[1], sbq[1], B, slots + 1, wslot + 1, slots + 2);
  conv_mfma<16, 56, 16, false, false, 1><<<784, 256, 0, stream>>>(
      B, wq[2], sgq[2], sbq[2], A, slots + 2, wslot + 2, slots + 3);
  conv_lds<16, 56, 32, false, 16><<<16 * 16, 256, 0, stream>>>(
      A, wq[3], sgq[3], sbq[3], B, slots + 3, wslot + 3, slots + 4);
  conv_mfma<32, 56, 32, false, false, 2><<<1568, 256, 0, stream>>>(
      B, wq[4], sgq[4], sbq[4], A, slots + 4, wslot + 4, slots + 5);
  conv_lds<32, 56, 64, true, 16><<<16 * 16, 256, 0, stream>>>(
      A, wq[5], sgq[5], sbq[5], B, slots + 5, wslot + 5, slots + 6);
  conv_mfma<64, 28, 32, false, false, 2><<<392, 256, 0, stream>>>(
      B, wq[6], sgq[6], sbq[6], A, slots + 6, wslot + 6, slots + 7);
  conv_lds<32, 28, 64, false, 8><<<16 * 16, 256, 0, stream>>>(
      A, wq[7], sgq[7], sbq[7], B, slots + 7, wslot + 7, slots + 8);
  conv_mfma<64, 28, 32, false, false, 2><<<392, 256, 0, stream>>>(
      B, wq[8], sgq[8], sbq[8], A, slots + 8, wslot + 8, slots + 9);
  conv_lds<32, 28, 64, false, 8><<<16 * 16, 256, 0, stream>>>(
      A, wq[9], sgq[9], sbq[9], B, slots + 9, wslot + 9, slots + 10);
  conv_mfma<64, 28, 32, false, false, 2><<<392, 256, 0, stream>>>(
      B, wq[10], sgq[10], sbq[10], A, slots + 10, wslot + 10, slots + 11);
  conv_lds<32, 28, 64, false, 8><<<16 * 16, 256, 0, stream>>>(
      A, wq[11], sgq[11], sbq[11], B, slots + 11, wslot + 11, slots + 12);

  avgpool_kernel<<<16, 1024, 0, stream>>>(B, P, slots + 12, slots + 13);
  tail_kernel<<<1, 256, 0, stream>>>(P, fw1q, fb1q, fw2q, fb2q, slots + 13,
                                     (float*)d_out);
}